// Round 4
// baseline (927.095 us; speedup 1.0000x reference)
//
#include <hip/hip_runtime.h>

#define T 2048
#define HID 4096
#define NH 32
#define NKV 8
#define HD 128
#define QKV_OUT ((NH + 2*NKV) * HD)   // 6144
#define SCALING 0.08838834764831843f  // 128^-0.5

typedef __attribute__((ext_vector_type(8))) short bfrag;   // 8 bf16
typedef __attribute__((ext_vector_type(4))) float ffrag;   // 4 f32 acc

__device__ __forceinline__ short f2bf(float f) {
  unsigned u = __builtin_bit_cast(unsigned, f);
  u += 0x7fffu + ((u >> 16) & 1u);   // RNE; exact for ints <= 255
  return (short)(u >> 16);
}

// bf16x2 split: x ~= hi + lo, residual ~2^-17 * |x|
__device__ __forceinline__ void split2(float x, short& hi, short& lo) {
  unsigned u = __builtin_bit_cast(unsigned, x);
  unsigned uh = u + (0x7fffu + ((u >> 16) & 1u));
  hi = (short)(uh >> 16);
  float fh = __builtin_bit_cast(float, uh & 0xffff0000u);
  float r = x - fh;                  // exact in fp32
  unsigned ur = __builtin_bit_cast(unsigned, r);
  ur += 0x7fffu + ((ur >> 16) & 1u);
  lo = (short)(ur >> 16);
}

// async global->LDS, 16 B per lane; LDS dst = wave-uniform base + lane*16
__device__ __forceinline__ void gload_lds16(const void* g, void* l) {
  __builtin_amdgcn_global_load_lds(
      (const __attribute__((address_space(1))) unsigned int*)g,
      (__attribute__((address_space(3))) unsigned int*)l, 16, 0, 0);
}

// ---------------- a_sum ----------------
__global__ __launch_bounds__(256)
void asum_kernel(const int* __restrict__ qact, float* __restrict__ a_sum) {
  __shared__ int red[256];
  const int t = blockIdx.x, tid = threadIdx.x;
  const int4* row = (const int4*)(qact + (size_t)t * HID);
  int s = 0;
#pragma unroll
  for (int i = 0; i < 4; i++) {
    int4 v = row[tid + 256 * i];
    s += v.x + v.y + v.z + v.w;
  }
  red[tid] = s; __syncthreads();
  for (int off = 128; off > 0; off >>= 1) {
    if (tid < off) red[tid] += red[tid + off];
    __syncthreads();
  }
  if (tid == 0) a_sum[t] = (float)red[0];
}

// ---------------- int32 -> bf16 (exact for |v|<=255) ----------------
__global__ __launch_bounds__(256)
void conv_i2b(const int* __restrict__ src, short* __restrict__ dst, int n8) {
  int idx = blockIdx.x * 256 + threadIdx.x;
  if (idx >= n8) return;
  const int4* s4 = (const int4*)src + (size_t)idx * 2;
  int4 a = s4[0], b = s4[1];
  bfrag h;
  h[0] = f2bf((float)a.x); h[1] = f2bf((float)a.y);
  h[2] = f2bf((float)a.z); h[3] = f2bf((float)a.w);
  h[4] = f2bf((float)b.x); h[5] = f2bf((float)b.y);
  h[6] = f2bf((float)b.z); h[7] = f2bf((float)b.w);
  *(bfrag*)(dst + (size_t)idx * 8) = h;
}

// ---------------- W4A8 GEMM (m97 structure): C = sa*sw*(A*W^T - zw*asum) ----
// A: M x K bf16. W: N x K bf16 (WBF) or int32 (fallback).
// 128x128 tile, BK=32, unpadded LDS, global_load_lds width 16.
template<bool WBF>
__global__ __launch_bounds__(256)
void gemm_w4a8(const short* __restrict__ A, const void* __restrict__ Wv,
               const float* __restrict__ s_a, const float* __restrict__ asum,
               const float* __restrict__ s_w, const float* __restrict__ z_w,
               float* __restrict__ C, int M, int N, int K) {
  __shared__ __align__(16) short As[128 * 32];
  __shared__ __align__(16) short Bs[128 * 32];
  const int tid = threadIdx.x;
  const int lane = tid & 63;
  const int quad = lane >> 4, l15 = lane & 15;
  const int wave = tid >> 6;
  const int wm = (wave >> 1) * 64, wn = (wave & 1) * 64;
  const int bm = blockIdx.y * 128, bn = blockIdx.x * 128;
  const int rr = tid >> 2, cc8 = (tid & 3) * 8;   // staging row / col (shorts)

  ffrag acc[4][4];
#pragma unroll
  for (int mi = 0; mi < 4; mi++)
#pragma unroll
    for (int ni = 0; ni < 4; ni++)
      acc[mi][ni] = (ffrag){0.f, 0.f, 0.f, 0.f};

  for (int k0 = 0; k0 < K; k0 += 32) {
#pragma unroll
    for (int it = 0; it < 2; it++) {
      gload_lds16(A + (size_t)(bm + it * 64 + rr) * K + k0 + cc8,
                  &As[it * 2048 + wave * 512]);
    }
    if constexpr (WBF) {
      const short* W = (const short*)Wv;
#pragma unroll
      for (int it = 0; it < 2; it++) {
        gload_lds16(W + (size_t)(bn + it * 64 + rr) * K + k0 + cc8,
                    &Bs[it * 2048 + wave * 512]);
      }
    } else {
      const int* W = (const int*)Wv;
#pragma unroll
      for (int i = 0; i < 4; i++) {
        int e = tid + 256 * i;
        int r = e >> 3, c = e & 7;
        int4 v = *(const int4*)(W + (size_t)(bn + r) * K + k0 + c * 4);
        short4 h;
        h.x = f2bf((float)v.x); h.y = f2bf((float)v.y);
        h.z = f2bf((float)v.z); h.w = f2bf((float)v.w);
        *(short4*)&Bs[r * 32 + c * 4] = h;
      }
    }
    __syncthreads();

    bfrag af[4], bfv[4];
#pragma unroll
    for (int mi = 0; mi < 4; mi++)
      af[mi] = *(const bfrag*)&As[(wm + mi * 16 + l15) * 32 + quad * 8];
#pragma unroll
    for (int ni = 0; ni < 4; ni++)
      bfv[ni] = *(const bfrag*)&Bs[(wn + ni * 16 + l15) * 32 + quad * 8];
#pragma unroll
    for (int mi = 0; mi < 4; mi++)
#pragma unroll
      for (int ni = 0; ni < 4; ni++)
        acc[mi][ni] = __builtin_amdgcn_mfma_f32_16x16x32_bf16(
            af[mi], bfv[ni], acc[mi][ni], 0, 0, 0);
    __syncthreads();
  }

#pragma unroll
  for (int mi = 0; mi < 4; mi++) {
    int row0 = bm + wm + mi * 16 + quad * 4;
#pragma unroll
    for (int r = 0; r < 4; r++) {
      int row = row0 + r;
      float sa = s_a[row], av = asum[row];
#pragma unroll
      for (int ni = 0; ni < 4; ni++) {
        int col = bn + wn + ni * 16 + l15;
        C[(size_t)row * N + col] = (sa * s_w[col]) * (acc[mi][ni][r] - z_w[col] * av);
      }
    }
  }
}

// ---------------- RoPE (in-place) ----------------
__global__ __launch_bounds__(64)
void rope_kernel(float* __restrict__ qkv, const int* __restrict__ positions) {
  const int b = blockIdx.x;
  const int t = b / (NH + NKV);
  const int h = b % (NH + NKV);
  float* base = qkv + (size_t)t * QKV_OUT + (size_t)h * HD;
  const int i = threadIdx.x;
  float inv = exp2f(-0.20762050593046014f * (float)i);  // 10000^(-i/64)
  float f = (float)positions[t] * inv;
  float s, c;
  sincosf(f, &s, &c);
  float x1 = base[i], x2 = base[i + 64];
  base[i]      = x1 * c - x2 * s;
  base[i + 64] = x2 * c + x1 * s;
}

// ---------------- split K/V into bf16 hi/lo; V transposed ----------------
// Kh/Kl: [NKV][T][HD]. Vth/Vtl: [NKV][HD][T].
__global__ __launch_bounds__(256)
void split_kv(const float* __restrict__ qkv,
              short* __restrict__ Kh, short* __restrict__ Kl,
              short* __restrict__ Vth, short* __restrict__ Vtl) {
  __shared__ __align__(16) short Vh_lds[128 * 72];
  __shared__ __align__(16) short Vl_lds[128 * 72];
  const int kvh = blockIdx.y;
  const int t0 = blockIdx.x * 64;
  const int tid = threadIdx.x;
#pragma unroll
  for (int i = 0; i < 8; i++) {
    int c = tid + 256 * i;
    int key = c >> 5, dc = c & 31;
    float4 f = *(const float4*)(qkv + (size_t)(t0 + key) * QKV_OUT
                                + (size_t)NH * HD + (size_t)kvh * HD + dc * 4);
    short4 h4, l4;
    split2(f.x, h4.x, l4.x); split2(f.y, h4.y, l4.y);
    split2(f.z, h4.z, l4.z); split2(f.w, h4.w, l4.w);
    size_t o = (size_t)kvh * T * HD + (size_t)(t0 + key) * HD + dc * 4;
    *(short4*)(Kh + o) = h4;
    *(short4*)(Kl + o) = l4;
  }
#pragma unroll
  for (int i = 0; i < 8; i++) {
    int c = tid + 256 * i;
    int key = c >> 5, dc = c & 31;
    float4 f = *(const float4*)(qkv + (size_t)(t0 + key) * QKV_OUT
                                + (size_t)(NH + NKV) * HD + (size_t)kvh * HD + dc * 4);
    short hi, lo;
    split2(f.x, hi, lo); Vh_lds[(dc*4+0)*72 + key] = hi; Vl_lds[(dc*4+0)*72 + key] = lo;
    split2(f.y, hi, lo); Vh_lds[(dc*4+1)*72 + key] = hi; Vl_lds[(dc*4+1)*72 + key] = lo;
    split2(f.z, hi, lo); Vh_lds[(dc*4+2)*72 + key] = hi; Vl_lds[(dc*4+2)*72 + key] = lo;
    split2(f.w, hi, lo); Vh_lds[(dc*4+3)*72 + key] = hi; Vl_lds[(dc*4+3)*72 + key] = lo;
  }
  __syncthreads();
#pragma unroll
  for (int i = 0; i < 4; i++) {
    int c = tid + 256 * i;
    int row = c >> 3, cc = c & 7;
    size_t o = (size_t)kvh * HD * T + (size_t)row * T + t0 + cc * 8;
    *(bfrag*)(Vth + o) = *(const bfrag*)&Vh_lds[row * 72 + cc * 8];
    *(bfrag*)(Vtl + o) = *(const bfrag*)&Vl_lds[row * 72 + cc * 8];
  }
}

// ---------------- MFMA flash attention ----------------
// Block: (kvh, 32 q rows). Wave wv = q-head kvh*4+wv, two 16-row fragments.
// K/V staged once per block (shared by 4 heads); K frag reads shared by the
// 2 row fragments. S: Qh*Kh+Qh*Kl+Ql*Kh. PV: Pbf16*(Vh+Vl). l via ones-MFMA.
__global__ __launch_bounds__(256, 2)
void attn_kernel(const float* __restrict__ qkv,
                 const short* __restrict__ Kh, const short* __restrict__ Kl,
                 const short* __restrict__ Vth, const short* __restrict__ Vtl,
                 float* __restrict__ attn) {
  __shared__ __align__(16) short Ksh[32 * 136];   // pitch 136: +4 banks/row
  __shared__ __align__(16) short Ksl[32 * 136];
  __shared__ __align__(16) short Vsh[128 * 40];   // pitch 40: +20 banks/row
  __shared__ __align__(16) short Vsl[128 * 40];
  __shared__ __align__(16) short Psh[4 * 32 * 40];

  const int kvh = blockIdx.y;
  const int qt = gridDim.x - 1 - blockIdx.x;   // heavy first
  const int q0 = qt * 32;
  const int tid = threadIdx.x;
  const int lane = tid & 63;
  const int wv = tid >> 6;
  const int l15 = lane & 15, quad = lane >> 4;
  const int h = kvh * 4 + wv;
  short* Pw = Psh + wv * 32 * 40;

  // Q fragments for two rowsets: row q0+rs*16+l15, dims kc*32+quad*8+j
  bfrag qh[2][4], ql[2][4];
#pragma unroll
  for (int rs = 0; rs < 2; rs++) {
    const float* qrow = qkv + (size_t)(q0 + rs * 16 + l15) * QKV_OUT + (size_t)h * HD;
#pragma unroll
    for (int kc = 0; kc < 4; kc++) {
      float4 f0 = *(const float4*)(qrow + kc * 32 + quad * 8);
      float4 f1 = *(const float4*)(qrow + kc * 32 + quad * 8 + 4);
      float fv[8] = {f0.x, f0.y, f0.z, f0.w, f1.x, f1.y, f1.z, f1.w};
#pragma unroll
      for (int j = 0; j < 8; j++) {
        short hi, lo; split2(fv[j], hi, lo);
        qh[rs][kc][j] = hi; ql[rs][kc][j] = lo;
      }
    }
  }

  bfrag ones;
#pragma unroll
  for (int j = 0; j < 8; j++) ones[j] = (short)0x3f80;  // bf16 1.0

  ffrag o[2][8], ol[2];
#pragma unroll
  for (int rs = 0; rs < 2; rs++) {
    ol[rs] = (ffrag){0.f, 0.f, 0.f, 0.f};
#pragma unroll
    for (int n = 0; n < 8; n++) o[rs][n] = (ffrag){0.f, 0.f, 0.f, 0.f};
  }
  float m_i[2][4] = {{-1e30f,-1e30f,-1e30f,-1e30f},{-1e30f,-1e30f,-1e30f,-1e30f}};

  const short* KhB = Kh + (size_t)kvh * T * HD;
  const short* KlB = Kl + (size_t)kvh * T * HD;
  const short* VhB = Vth + (size_t)kvh * HD * T;
  const short* VlB = Vtl + (size_t)kvh * HD * T;
  const int nk = (q0 >> 5) + 1;                // keys 0..q0+31

  for (int kt = 0; kt < nk; kt++) {
    const int k0 = kt << 5;
    __syncthreads();
    // stage K [key][d] hi/lo — pure b128 copies
#pragma unroll
    for (int i = 0; i < 2; i++) {
      int c = tid + 256 * i;
      int r = c >> 4, cc = c & 15;
      *(bfrag*)&Ksh[r * 136 + cc * 8] = *(const bfrag*)(KhB + (size_t)(k0 + r) * HD + cc * 8);
      *(bfrag*)&Ksl[r * 136 + cc * 8] = *(const bfrag*)(KlB + (size_t)(k0 + r) * HD + cc * 8);
    }
    // stage V [d][key] hi/lo
#pragma unroll
    for (int i = 0; i < 2; i++) {
      int c = tid + 256 * i;
      int d = c >> 2, cc = c & 3;
      *(bfrag*)&Vsh[d * 40 + cc * 8] = *(const bfrag*)(VhB + (size_t)d * T + k0 + cc * 8);
      *(bfrag*)&Vsl[d * 40 + cc * 8] = *(const bfrag*)(VlB + (size_t)d * T + k0 + cc * 8);
    }
    __syncthreads();

    // ---- S = Q K^T; K fragments shared across the two rowsets ----
    ffrag s[2][2];
    s[0][0] = (ffrag){0.f,0.f,0.f,0.f}; s[0][1] = (ffrag){0.f,0.f,0.f,0.f};
    s[1][0] = (ffrag){0.f,0.f,0.f,0.f}; s[1][1] = (ffrag){0.f,0.f,0.f,0.f};
#pragma unroll
    for (int n = 0; n < 2; n++) {
#pragma unroll
      for (int kc = 0; kc < 4; kc++) {
        bfrag bh = *(const bfrag*)&Ksh[(n*16 + l15) * 136 + kc*32 + quad*8];
        bfrag bl = *(const bfrag*)&Ksl[(n*16 + l15) * 136 + kc*32 + quad*8];
#pragma unroll
        for (int rs = 0; rs < 2; rs++) {
          s[rs][n] = __builtin_amdgcn_mfma_f32_16x16x32_bf16(qh[rs][kc], bh, s[rs][n], 0,0,0);
          s[rs][n] = __builtin_amdgcn_mfma_f32_16x16x32_bf16(qh[rs][kc], bl, s[rs][n], 0,0,0);
          s[rs][n] = __builtin_amdgcn_mfma_f32_16x16x32_bf16(ql[rs][kc], bh, s[rs][n], 0,0,0);
        }
      }
    }
    // ---- online softmax per rowset ----
    const bool last = (kt == nk - 1);
#pragma unroll
    for (int rs = 0; rs < 2; rs++) {
      float sv[2][4];
#pragma unroll
      for (int n = 0; n < 2; n++)
#pragma unroll
        for (int r = 0; r < 4; r++) {
          float v = s[rs][n][r] * SCALING;
          if (last) {
            int key = k0 + n * 16 + l15;
            int row = q0 + rs * 16 + quad * 4 + r;
            if (key > row) v = -1e30f;
          }
          sv[n][r] = v;
        }
      float alpha[4];
#pragma unroll
      for (int r = 0; r < 4; r++) {
        float mt = fmaxf(sv[0][r], sv[1][r]);
        mt = fmaxf(mt, __shfl_xor(mt, 1));
        mt = fmaxf(mt, __shfl_xor(mt, 2));
        mt = fmaxf(mt, __shfl_xor(mt, 4));
        mt = fmaxf(mt, __shfl_xor(mt, 8));
        float m_new = fmaxf(m_i[rs][r], mt);
        alpha[r] = __expf(m_i[rs][r] - m_new);
        m_i[rs][r] = m_new;
      }
#pragma unroll
      for (int n = 0; n < 2; n++)
#pragma unroll
        for (int r = 0; r < 4; r++) {
          float p = __expf(sv[n][r] - m_i[rs][r]);
          Pw[(rs*16 + quad*4 + r) * 40 + n*16 + l15] = f2bf(p);
        }
      // rescale O and l-accumulator
#pragma unroll
      for (int r = 0; r < 4; r++) ol[rs][r] *= alpha[r];
#pragma unroll
      for (int n = 0; n < 8; n++)
#pragma unroll
        for (int r = 0; r < 4; r++) o[rs][n][r] *= alpha[r];
    }
    // ---- PV; V fragments shared across rowsets; l via ones-MFMA ----
    bfrag ph0 = *(const bfrag*)&Pw[(l15) * 40 + quad * 8];
    bfrag ph1 = *(const bfrag*)&Pw[(16 + l15) * 40 + quad * 8];
    ol[0] = __builtin_amdgcn_mfma_f32_16x16x32_bf16(ph0, ones, ol[0], 0,0,0);
    ol[1] = __builtin_amdgcn_mfma_f32_16x16x32_bf16(ph1, ones, ol[1], 0,0,0);
#pragma unroll
    for (int n = 0; n < 8; n++) {
      bfrag vh = *(const bfrag*)&Vsh[(n*16 + l15) * 40 + quad * 8];
      bfrag vl = *(const bfrag*)&Vsl[(n*16 + l15) * 40 + quad * 8];
      o[0][n] = __builtin_amdgcn_mfma_f32_16x16x32_bf16(ph0, vh, o[0][n], 0,0,0);
      o[0][n] = __builtin_amdgcn_mfma_f32_16x16x32_bf16(ph0, vl, o[0][n], 0,0,0);
      o[1][n] = __builtin_amdgcn_mfma_f32_16x16x32_bf16(ph1, vh, o[1][n], 0,0,0);
      o[1][n] = __builtin_amdgcn_mfma_f32_16x16x32_bf16(ph1, vl, o[1][n], 0,0,0);
    }
  }

#pragma unroll
  for (int rs = 0; rs < 2; rs++) {
    float inv[4];
#pragma unroll
    for (int r = 0; r < 4; r++) inv[r] = 1.f / ol[rs][r];
#pragma unroll
    for (int n = 0; n < 8; n++)
#pragma unroll
      for (int r = 0; r < 4; r++) {
        int row = q0 + rs * 16 + quad * 4 + r;
        attn[(size_t)row * HID + (size_t)h * HD + n * 16 + l15] = o[rs][n][r] * inv[r];
      }
  }
}

// ---------------- dynamic quant with sum ----------------
__global__ __launch_bounds__(256)
void quant_kernel(const float* __restrict__ x, short* __restrict__ q2,
                  float* __restrict__ s2, float* __restrict__ sum2) {
  __shared__ float red[256];
  const int t = blockIdx.x, tid = threadIdx.x;
  const float* row = x + (size_t)t * HID;
  float4 v[4];
  float m = 0.f;
#pragma unroll
  for (int i = 0; i < 4; i++) {
    v[i] = *(const float4*)(row + (tid + 256 * i) * 4);
    m = fmaxf(m, fmaxf(fmaxf(fabsf(v[i].x), fabsf(v[i].y)),
                       fmaxf(fabsf(v[i].z), fabsf(v[i].w))));
  }
  red[tid] = m; __syncthreads();
  for (int off = 128; off > 0; off >>= 1) {
    if (tid < off) red[tid] = fmaxf(red[tid], red[tid + off]);
    __syncthreads();
  }
  float s = fmaxf(red[0], 1e-8f) / 127.f;
  __syncthreads();
  float ssum = 0.f;
#pragma unroll
  for (int i = 0; i < 4; i++) {
    short4 h; float q;
    q = fminf(127.f, fmaxf(-127.f, rintf(v[i].x / s))); ssum += q; h.x = f2bf(q);
    q = fminf(127.f, fmaxf(-127.f, rintf(v[i].y / s))); ssum += q; h.y = f2bf(q);
    q = fminf(127.f, fmaxf(-127.f, rintf(v[i].z / s))); ssum += q; h.z = f2bf(q);
    q = fminf(127.f, fmaxf(-127.f, rintf(v[i].w / s))); ssum += q; h.w = f2bf(q);
    *(short4*)(q2 + (size_t)t * HID + (tid + 256 * i) * 4) = h;
  }
  red[tid] = ssum; __syncthreads();
  for (int off = 128; off > 0; off >>= 1) {
    if (tid < off) red[tid] += red[tid + off];
    __syncthreads();
  }
  if (tid == 0) { s2[t] = s; sum2[t] = red[0]; }
}

// ---------------- launch ----------------
extern "C" void kernel_launch(void* const* d_in, const int* in_sizes, int n_in,
                              void* d_out, int out_size, void* d_ws, size_t ws_size,
                              hipStream_t stream) {
  const int*   positions   = (const int*)d_in[0];
  const int*   q_act       = (const int*)d_in[1];
  const float* act_scale   = (const float*)d_in[2];
  const int*   w_qkv_q     = (const int*)d_in[3];
  const float* w_qkv_scale = (const float*)d_in[4];
  const float* w_qkv_zero  = (const float*)d_in[5];
  const int*   w_o_q       = (const int*)d_in[6];
  const float* w_o_scale   = (const float*)d_in[7];
  const float* w_o_zero    = (const float*)d_in[8];
  float* out = (float*)d_out;

  size_t off = 0;
  auto alloc = [&](size_t bytes) -> void* {
    void* p = (char*)d_ws + off;
    off += (bytes + 255) & ~(size_t)255;
    return p;
  };
  float* qkv   = (float*)alloc((size_t)T * QKV_OUT * 4);
  short* a_bf  = (short*)alloc((size_t)T * HID * 2);
  short* q2    = (short*)alloc((size_t)T * HID * 2);
  short* Kh    = (short*)alloc((size_t)NKV * T * HD * 2);
  short* Kl    = (short*)alloc((size_t)NKV * T * HD * 2);
  short* Vth   = (short*)alloc((size_t)NKV * T * HD * 2);
  short* Vtl   = (short*)alloc((size_t)NKV * T * HD * 2);
  float* a_sum = (float*)alloc(T * 4);
  float* s2    = (float*)alloc(T * 4);
  float* sum2  = (float*)alloc(T * 4);
  short* wqkv_bf = (short*)alloc((size_t)QKV_OUT * HID * 2);
  short* wo_bf   = (short*)alloc((size_t)HID * HID * 2);
  const bool wconv = (ws_size >= off);   // constant across calls

  asum_kernel<<<T, 256, 0, stream>>>(q_act, a_sum);
  conv_i2b<<<(T * HID / 8 + 255) / 256, 256, 0, stream>>>(q_act, a_bf, T * HID / 8);
  if (wconv) {
    conv_i2b<<<(QKV_OUT * HID / 8 + 255) / 256, 256, 0, stream>>>(w_qkv_q, wqkv_bf, QKV_OUT * HID / 8);
    conv_i2b<<<(HID * HID / 8 + 255) / 256, 256, 0, stream>>>(w_o_q, wo_bf, HID * HID / 8);
    gemm_w4a8<true><<<dim3(QKV_OUT / 128, T / 128), 256, 0, stream>>>(
        a_bf, wqkv_bf, act_scale, a_sum, w_qkv_scale, w_qkv_zero, qkv, T, QKV_OUT, HID);
  } else {
    gemm_w4a8<false><<<dim3(QKV_OUT / 128, T / 128), 256, 0, stream>>>(
        a_bf, w_qkv_q, act_scale, a_sum, w_qkv_scale, w_qkv_zero, qkv, T, QKV_OUT, HID);
  }
  rope_kernel<<<T * (NH + NKV), 64, 0, stream>>>(qkv, positions);
  split_kv<<<dim3(T / 64, NKV), 256, 0, stream>>>(qkv, Kh, Kl, Vth, Vtl);
  attn_kernel<<<dim3(T / 32, NKV), 256, 0, stream>>>(qkv, Kh, Kl, Vth, Vtl, out);
  quant_kernel<<<T, 256, 0, stream>>>(out, q2, s2, sum2);
  if (wconv) {
    gemm_w4a8<true><<<dim3(HID / 128, T / 128), 256, 0, stream>>>(
        q2, wo_bf, s2, sum2, w_o_scale, w_o_zero, out, T, HID, HID);
  } else {
    gemm_w4a8<false><<<dim3(HID / 128, T / 128), 256, 0, stream>>>(
        q2, w_o_q, s2, sum2, w_o_scale, w_o_zero, out, T, HID, HID);
  }
}

// Round 5
// 912.355 us; speedup vs baseline: 1.0162x; 1.0162x over previous
//
#include <hip/hip_runtime.h>

#define T 2048
#define HID 4096
#define NH 32
#define NKV 8
#define HD 128
#define QKV_OUT ((NH + 2*NKV) * HD)   // 6144
#define SCALING 0.08838834764831843f  // 128^-0.5

typedef __attribute__((ext_vector_type(8))) short bfrag;   // 8 bf16
typedef __attribute__((ext_vector_type(4))) float ffrag;   // 4 f32 acc
typedef __attribute__((ext_vector_type(4))) int  ifrag;    // 16 i8 / 4 i32 acc
typedef __attribute__((ext_vector_type(16))) char c16;

__device__ __forceinline__ short f2bf(float f) {
  unsigned u = __builtin_bit_cast(unsigned, f);
  u += 0x7fffu + ((u >> 16) & 1u);   // RNE
  return (short)(u >> 16);
}
__device__ __forceinline__ float bf2f(unsigned short s) {
  unsigned u = (unsigned)s << 16;
  return __builtin_bit_cast(float, u);
}

// bf16x2 split: x ~= hi + lo, residual ~2^-17 * |x|
__device__ __forceinline__ void split2(float x, short& hi, short& lo) {
  unsigned u = __builtin_bit_cast(unsigned, x);
  unsigned uh = u + (0x7fffu + ((u >> 16) & 1u));
  hi = (short)(uh >> 16);
  float fh = __builtin_bit_cast(float, uh & 0xffff0000u);
  float r = x - fh;
  unsigned ur = __builtin_bit_cast(unsigned, r);
  ur += 0x7fffu + ((ur >> 16) & 1u);
  lo = (short)(ur >> 16);
}

// async global->LDS, 16 B per lane; LDS dst = wave-uniform base + lane*16
__device__ __forceinline__ void gload_lds16(const void* g, void* l) {
  __builtin_amdgcn_global_load_lds(
      (const __attribute__((address_space(1))) unsigned int*)g,
      (__attribute__((address_space(3))) unsigned int*)l, 16, 0, 0);
}

// ---------------- a_sum ----------------
__global__ __launch_bounds__(256)
void asum_kernel(const int* __restrict__ qact, float* __restrict__ a_sum) {
  __shared__ int red[256];
  const int t = blockIdx.x, tid = threadIdx.x;
  const int4* row = (const int4*)(qact + (size_t)t * HID);
  int s = 0;
#pragma unroll
  for (int i = 0; i < 4; i++) {
    int4 v = row[tid + 256 * i];
    s += v.x + v.y + v.z + v.w;
  }
  red[tid] = s; __syncthreads();
  for (int off = 128; off > 0; off >>= 1) {
    if (tid < off) red[tid] += red[tid + off];
    __syncthreads();
  }
  if (tid == 0) a_sum[t] = (float)red[0];
}

// ---------------- int32 -> int8 pack (values fit i8) ----------------
__global__ __launch_bounds__(256)
void conv_i2c(const int* __restrict__ src, char* __restrict__ dst, int n16) {
  int idx = blockIdx.x * 256 + threadIdx.x;
  if (idx >= n16) return;
  const int4* s4 = (const int4*)src + (size_t)idx * 4;
  c16 o;
#pragma unroll
  for (int j = 0; j < 4; j++) {
    int4 v = s4[j];
    o[j*4+0] = (char)v.x; o[j*4+1] = (char)v.y;
    o[j*4+2] = (char)v.z; o[j*4+3] = (char)v.w;
  }
  *(c16*)(dst + (size_t)idx * 16) = o;
}

// ---------------- W4A8 GEMM, exact i8 MFMA: C = sa*sw*(A*W^T - zw*asum) ----
// A: M x K i8. W: N x K i8 (WI8) or int32 (fallback pack). 128x128 tile, BK=64.
template<bool WI8>
__global__ __launch_bounds__(256)
void gemm_i8(const char* __restrict__ A, const void* __restrict__ Wv,
             const float* __restrict__ s_a, const float* __restrict__ asum,
             const float* __restrict__ s_w, const float* __restrict__ z_w,
             float* __restrict__ C, int M, int N, int K) {
  __shared__ __align__(16) char As[128 * 64];
  __shared__ __align__(16) char Bs[128 * 64];
  const int tid = threadIdx.x;
  const int lane = tid & 63;
  const int quad = lane >> 4, l15 = lane & 15;
  const int wave = tid >> 6;
  const int wm = (wave >> 1) * 64, wn = (wave & 1) * 64;
  const int bm = blockIdx.y * 128, bn = blockIdx.x * 128;
  const int sr = tid >> 2, sc = (tid & 3) * 16;   // staging row / byte-col

  ifrag acc[4][4];
#pragma unroll
  for (int mi = 0; mi < 4; mi++)
#pragma unroll
    for (int ni = 0; ni < 4; ni++)
      acc[mi][ni] = (ifrag){0, 0, 0, 0};

  for (int k0 = 0; k0 < K; k0 += 64) {
#pragma unroll
    for (int it = 0; it < 2; it++)
      gload_lds16(A + (size_t)(bm + it * 64 + sr) * K + k0 + sc,
                  &As[it * 4096 + wave * 1024]);
    if constexpr (WI8) {
      const char* W = (const char*)Wv;
#pragma unroll
      for (int it = 0; it < 2; it++)
        gload_lds16(W + (size_t)(bn + it * 64 + sr) * K + k0 + sc,
                    &Bs[it * 4096 + wave * 1024]);
    } else {
      const int* W = (const int*)Wv;
      int r = tid >> 1, hh = (tid & 1) * 32;
#pragma unroll
      for (int i = 0; i < 2; i++) {
        c16 o;
#pragma unroll
        for (int j = 0; j < 4; j++) {
          int4 v = *(const int4*)(W + (size_t)(bn + r) * K + k0 + hh + i * 16 + j * 4);
          o[j*4+0] = (char)v.x; o[j*4+1] = (char)v.y;
          o[j*4+2] = (char)v.z; o[j*4+3] = (char)v.w;
        }
        *(c16*)&Bs[r * 64 + hh + i * 16] = o;
      }
    }
    __syncthreads();

    ifrag af[4], bfv[4];
#pragma unroll
    for (int mi = 0; mi < 4; mi++)
      af[mi] = *(const ifrag*)&As[(wm + mi * 16 + l15) * 64 + quad * 16];
#pragma unroll
    for (int ni = 0; ni < 4; ni++)
      bfv[ni] = *(const ifrag*)&Bs[(wn + ni * 16 + l15) * 64 + quad * 16];
#pragma unroll
    for (int mi = 0; mi < 4; mi++)
#pragma unroll
      for (int ni = 0; ni < 4; ni++)
        acc[mi][ni] = __builtin_amdgcn_mfma_i32_16x16x64_i8(
            af[mi], bfv[ni], acc[mi][ni], 0, 0, 0);
    __syncthreads();
  }

#pragma unroll
  for (int mi = 0; mi < 4; mi++) {
    int row0 = bm + wm + mi * 16 + quad * 4;
#pragma unroll
    for (int r = 0; r < 4; r++) {
      int row = row0 + r;
      float sa = s_a[row], av = asum[row];
#pragma unroll
      for (int ni = 0; ni < 4; ni++) {
        int col = bn + wn + ni * 16 + l15;
        C[(size_t)row * N + col] = (sa * s_w[col]) * ((float)acc[mi][ni][r] - z_w[col] * av);
      }
    }
  }
}

// ---------------- RoPE (in-place) ----------------
__global__ __launch_bounds__(64)
void rope_kernel(float* __restrict__ qkv, const int* __restrict__ positions) {
  const int b = blockIdx.x;
  const int t = b / (NH + NKV);
  const int h = b % (NH + NKV);
  float* base = qkv + (size_t)t * QKV_OUT + (size_t)h * HD;
  const int i = threadIdx.x;
  float inv = exp2f(-0.20762050593046014f * (float)i);  // 10000^(-i/64)
  float f = (float)positions[t] * inv;
  float s, c;
  sincosf(f, &s, &c);
  float x1 = base[i], x2 = base[i + 64];
  base[i]      = x1 * c - x2 * s;
  base[i + 64] = x2 * c + x1 * s;
}

// ---------------- split K/V into bf16 hi/lo; V transposed ----------------
__global__ __launch_bounds__(256)
void split_kv(const float* __restrict__ qkv,
              short* __restrict__ Kh, short* __restrict__ Kl,
              short* __restrict__ Vth, short* __restrict__ Vtl) {
  __shared__ __align__(16) short Vh_lds[128 * 72];
  __shared__ __align__(16) short Vl_lds[128 * 72];
  const int kvh = blockIdx.y;
  const int t0 = blockIdx.x * 64;
  const int tid = threadIdx.x;
#pragma unroll
  for (int i = 0; i < 8; i++) {
    int c = tid + 256 * i;
    int key = c >> 5, dc = c & 31;
    float4 f = *(const float4*)(qkv + (size_t)(t0 + key) * QKV_OUT
                                + (size_t)NH * HD + (size_t)kvh * HD + dc * 4);
    short4 h4, l4;
    split2(f.x, h4.x, l4.x); split2(f.y, h4.y, l4.y);
    split2(f.z, h4.z, l4.z); split2(f.w, h4.w, l4.w);
    size_t o = (size_t)kvh * T * HD + (size_t)(t0 + key) * HD + dc * 4;
    *(short4*)(Kh + o) = h4;
    *(short4*)(Kl + o) = l4;
  }
#pragma unroll
  for (int i = 0; i < 8; i++) {
    int c = tid + 256 * i;
    int key = c >> 5, dc = c & 31;
    float4 f = *(const float4*)(qkv + (size_t)(t0 + key) * QKV_OUT
                                + (size_t)(NH + NKV) * HD + (size_t)kvh * HD + dc * 4);
    short hi, lo;
    split2(f.x, hi, lo); Vh_lds[(dc*4+0)*72 + key] = hi; Vl_lds[(dc*4+0)*72 + key] = lo;
    split2(f.y, hi, lo); Vh_lds[(dc*4+1)*72 + key] = hi; Vl_lds[(dc*4+1)*72 + key] = lo;
    split2(f.z, hi, lo); Vh_lds[(dc*4+2)*72 + key] = hi; Vl_lds[(dc*4+2)*72 + key] = lo;
    split2(f.w, hi, lo); Vh_lds[(dc*4+3)*72 + key] = hi; Vl_lds[(dc*4+3)*72 + key] = lo;
  }
  __syncthreads();
#pragma unroll
  for (int i = 0; i < 4; i++) {
    int c = tid + 256 * i;
    int row = c >> 3, cc = c & 7;
    size_t o = (size_t)kvh * HD * T + (size_t)row * T + t0 + cc * 8;
    *(bfrag*)(Vth + o) = *(const bfrag*)&Vh_lds[row * 72 + cc * 8];
    *(bfrag*)(Vtl + o) = *(const bfrag*)&Vl_lds[row * 72 + cc * 8];
  }
}

// ---------------- MFMA flash attention, split-K x2 partials ----------------
// Block: (kvh, 32 q rows, z). Wave wv = q-head kvh*4+wv. Group z processes
// ktiles z, z+2, ... Writes unnormalized O (bf16) + (m, l) per row.
__global__ __launch_bounds__(256, 3)
void attn_kernel(const float* __restrict__ qkv,
                 const short* __restrict__ Kh, const short* __restrict__ Kl,
                 const short* __restrict__ Vth, const short* __restrict__ Vtl,
                 short* __restrict__ op, float* __restrict__ ml) {
  __shared__ __align__(16) short Ksh[32 * 136];
  __shared__ __align__(16) short Ksl[32 * 136];
  __shared__ __align__(16) short Vsh[128 * 40];
  __shared__ __align__(16) short Vsl[128 * 40];
  __shared__ __align__(16) short Psh[4 * 32 * 40];

  const int kvh = blockIdx.y;
  const int bx = gridDim.x - 1 - blockIdx.x;   // heavy first
  const int qt = bx >> 1, z = bx & 1;
  const int q0 = qt * 32;
  const int tid = threadIdx.x;
  const int lane = tid & 63;
  const int wv = tid >> 6;
  const int l15 = lane & 15, quad = lane >> 4;
  const int h = kvh * 4 + wv;
  short* Pw = Psh + wv * 32 * 40;
  const int unit = (kvh * 64 + qt) * 2 + z;

  bfrag qh[2][4], ql[2][4];
#pragma unroll
  for (int rs = 0; rs < 2; rs++) {
    const float* qrow = qkv + (size_t)(q0 + rs * 16 + l15) * QKV_OUT + (size_t)h * HD;
#pragma unroll
    for (int kc = 0; kc < 4; kc++) {
      float4 f0 = *(const float4*)(qrow + kc * 32 + quad * 8);
      float4 f1 = *(const float4*)(qrow + kc * 32 + quad * 8 + 4);
      float fv[8] = {f0.x, f0.y, f0.z, f0.w, f1.x, f1.y, f1.z, f1.w};
#pragma unroll
      for (int j = 0; j < 8; j++) {
        short hi, lo; split2(fv[j], hi, lo);
        qh[rs][kc][j] = hi; ql[rs][kc][j] = lo;
      }
    }
  }

  bfrag ones;
#pragma unroll
  for (int j = 0; j < 8; j++) ones[j] = (short)0x3f80;

  ffrag o[2][8], ol[2];
#pragma unroll
  for (int rs = 0; rs < 2; rs++) {
    ol[rs] = (ffrag){0.f, 0.f, 0.f, 0.f};
#pragma unroll
    for (int n = 0; n < 8; n++) o[rs][n] = (ffrag){0.f, 0.f, 0.f, 0.f};
  }
  float m_i[2][4] = {{-1e30f,-1e30f,-1e30f,-1e30f},{-1e30f,-1e30f,-1e30f,-1e30f}};

  const short* KhB = Kh + (size_t)kvh * T * HD;
  const short* KlB = Kl + (size_t)kvh * T * HD;
  const short* VhB = Vth + (size_t)kvh * HD * T;
  const short* VlB = Vtl + (size_t)kvh * HD * T;
  const int nk = qt + 1;                       // ktiles 0..qt

  for (int kt = z; kt < nk; kt += 2) {
    const int k0 = kt << 5;
    __syncthreads();
#pragma unroll
    for (int i = 0; i < 2; i++) {
      int c = tid + 256 * i;
      int r = c >> 4, cc = c & 15;
      *(bfrag*)&Ksh[r * 136 + cc * 8] = *(const bfrag*)(KhB + (size_t)(k0 + r) * HD + cc * 8);
      *(bfrag*)&Ksl[r * 136 + cc * 8] = *(const bfrag*)(KlB + (size_t)(k0 + r) * HD + cc * 8);
    }
#pragma unroll
    for (int i = 0; i < 2; i++) {
      int c = tid + 256 * i;
      int d = c >> 2, cc = c & 3;
      *(bfrag*)&Vsh[d * 40 + cc * 8] = *(const bfrag*)(VhB + (size_t)d * T + k0 + cc * 8);
      *(bfrag*)&Vsl[d * 40 + cc * 8] = *(const bfrag*)(VlB + (size_t)d * T + k0 + cc * 8);
    }
    __syncthreads();

    ffrag s[2][2];
    s[0][0] = (ffrag){0.f,0.f,0.f,0.f}; s[0][1] = (ffrag){0.f,0.f,0.f,0.f};
    s[1][0] = (ffrag){0.f,0.f,0.f,0.f}; s[1][1] = (ffrag){0.f,0.f,0.f,0.f};
#pragma unroll
    for (int n = 0; n < 2; n++) {
#pragma unroll
      for (int kc = 0; kc < 4; kc++) {
        bfrag bh = *(const bfrag*)&Ksh[(n*16 + l15) * 136 + kc*32 + quad*8];
        bfrag bl = *(const bfrag*)&Ksl[(n*16 + l15) * 136 + kc*32 + quad*8];
#pragma unroll
        for (int rs = 0; rs < 2; rs++) {
          s[rs][n] = __builtin_amdgcn_mfma_f32_16x16x32_bf16(qh[rs][kc], bh, s[rs][n], 0,0,0);
          s[rs][n] = __builtin_amdgcn_mfma_f32_16x16x32_bf16(qh[rs][kc], bl, s[rs][n], 0,0,0);
          s[rs][n] = __builtin_amdgcn_mfma_f32_16x16x32_bf16(ql[rs][kc], bh, s[rs][n], 0,0,0);
        }
      }
    }
    const bool last = (kt == nk - 1);
#pragma unroll
    for (int rs = 0; rs < 2; rs++) {
      float sv[2][4];
#pragma unroll
      for (int n = 0; n < 2; n++)
#pragma unroll
        for (int r = 0; r < 4; r++) {
          float v = s[rs][n][r] * SCALING;
          if (last) {
            int key = k0 + n * 16 + l15;
            int row = q0 + rs * 16 + quad * 4 + r;
            if (key > row) v = -1e30f;
          }
          sv[n][r] = v;
        }
      float alpha[4];
#pragma unroll
      for (int r = 0; r < 4; r++) {
        float mt = fmaxf(sv[0][r], sv[1][r]);
        mt = fmaxf(mt, __shfl_xor(mt, 1));
        mt = fmaxf(mt, __shfl_xor(mt, 2));
        mt = fmaxf(mt, __shfl_xor(mt, 4));
        mt = fmaxf(mt, __shfl_xor(mt, 8));
        float m_new = fmaxf(m_i[rs][r], mt);
        alpha[r] = __expf(m_i[rs][r] - m_new);
        m_i[rs][r] = m_new;
      }
#pragma unroll
      for (int n = 0; n < 2; n++)
#pragma unroll
        for (int r = 0; r < 4; r++) {
          float p = __expf(sv[n][r] - m_i[rs][r]);
          Pw[(rs*16 + quad*4 + r) * 40 + n*16 + l15] = f2bf(p);
        }
#pragma unroll
      for (int r = 0; r < 4; r++) ol[rs][r] *= alpha[r];
#pragma unroll
      for (int n = 0; n < 8; n++)
#pragma unroll
        for (int r = 0; r < 4; r++) o[rs][n][r] *= alpha[r];
    }
    bfrag ph0 = *(const bfrag*)&Pw[(l15) * 40 + quad * 8];
    bfrag ph1 = *(const bfrag*)&Pw[(16 + l15) * 40 + quad * 8];
    ol[0] = __builtin_amdgcn_mfma_f32_16x16x32_bf16(ph0, ones, ol[0], 0,0,0);
    ol[1] = __builtin_amdgcn_mfma_f32_16x16x32_bf16(ph1, ones, ol[1], 0,0,0);
#pragma unroll
    for (int n = 0; n < 8; n++) {
      bfrag vh = *(const bfrag*)&Vsh[(n*16 + l15) * 40 + quad * 8];
      bfrag vl = *(const bfrag*)&Vsl[(n*16 + l15) * 40 + quad * 8];
      o[0][n] = __builtin_amdgcn_mfma_f32_16x16x32_bf16(ph0, vh, o[0][n], 0,0,0);
      o[0][n] = __builtin_amdgcn_mfma_f32_16x16x32_bf16(ph0, vl, o[0][n], 0,0,0);
      o[1][n] = __builtin_amdgcn_mfma_f32_16x16x32_bf16(ph1, vh, o[1][n], 0,0,0);
      o[1][n] = __builtin_amdgcn_mfma_f32_16x16x32_bf16(ph1, vl, o[1][n], 0,0,0);
    }
  }

  // store partials: O raw bf16, (m,l) f32
  size_t ubase = ((size_t)unit * 4 + wv) * 32;
#pragma unroll
  for (int rs = 0; rs < 2; rs++) {
#pragma unroll
    for (int r = 0; r < 4; r++) {
      int row32 = rs * 16 + quad * 4 + r;
      if (l15 == 0) {
        ml[(ubase + row32) * 2 + 0] = m_i[rs][r];
        ml[(ubase + row32) * 2 + 1] = ol[rs][r];
      }
#pragma unroll
      for (int n = 0; n < 8; n++)
        op[(ubase + row32) * 128 + n * 16 + l15] = f2bf(o[rs][n][r]);
    }
  }
}

// ---------------- combine split-K partials ----------------
__global__ __launch_bounds__(256)
void combine_kernel(const short* __restrict__ op, const float* __restrict__ ml,
                    float* __restrict__ attn) {
  int idx = blockIdx.x * 256 + threadIdx.x;    // over T*NH*32 d-groups
  int d4 = idx & 31;
  int h = (idx >> 5) & 31;
  int t = idx >> 10;
  int kvh = h >> 2, h4 = h & 3;
  int qt = t >> 5, row = t & 31;
  size_t u0 = ((size_t)(kvh * 64 + qt) * 2);
  size_t b0 = (u0 * 4 + h4) * 32 + row;
  size_t b1 = ((u0 + 1) * 4 + h4) * 32 + row;
  float m0 = ml[b0 * 2], l0 = ml[b0 * 2 + 1];
  float m1 = ml[b1 * 2], l1 = ml[b1 * 2 + 1];
  float mm = fmaxf(m0, m1);
  float w0 = __expf(m0 - mm), w1 = __expf(m1 - mm);
  float inv = 1.f / (w0 * l0 + w1 * l1);
  const unsigned short* p0 = (const unsigned short*)(op + b0 * 128 + d4 * 4);
  const unsigned short* p1 = (const unsigned short*)(op + b1 * 128 + d4 * 4);
  ushort4 a = *(const ushort4*)p0;
  ushort4 b = *(const ushort4*)p1;
  float4 r;
  r.x = (w0 * bf2f(a.x) + w1 * bf2f(b.x)) * inv;
  r.y = (w0 * bf2f(a.y) + w1 * bf2f(b.y)) * inv;
  r.z = (w0 * bf2f(a.z) + w1 * bf2f(b.z)) * inv;
  r.w = (w0 * bf2f(a.w) + w1 * bf2f(b.w)) * inv;
  *(float4*)(attn + (size_t)t * HID + (size_t)h * HD + d4 * 4) = r;
}

// ---------------- dynamic quant with sum (i8 out) ----------------
__global__ __launch_bounds__(256)
void quant_kernel(const float* __restrict__ x, char* __restrict__ q2,
                  float* __restrict__ s2, float* __restrict__ sum2) {
  __shared__ float red[256];
  const int t = blockIdx.x, tid = threadIdx.x;
  const float* row = x + (size_t)t * HID;
  float4 v[4];
  float m = 0.f;
#pragma unroll
  for (int i = 0; i < 4; i++) {
    v[i] = *(const float4*)(row + tid * 16 + i * 4);
    m = fmaxf(m, fmaxf(fmaxf(fabsf(v[i].x), fabsf(v[i].y)),
                       fmaxf(fabsf(v[i].z), fabsf(v[i].w))));
  }
  red[tid] = m; __syncthreads();
  for (int off = 128; off > 0; off >>= 1) {
    if (tid < off) red[tid] = fmaxf(red[tid], red[tid + off]);
    __syncthreads();
  }
  float s = fmaxf(red[0], 1e-8f) / 127.f;
  __syncthreads();
  float ssum = 0.f;
  c16 o;
#pragma unroll
  for (int i = 0; i < 4; i++) {
    float q;
    q = fminf(127.f, fmaxf(-127.f, rintf(v[i].x / s))); ssum += q; o[i*4+0] = (char)(int)q;
    q = fminf(127.f, fmaxf(-127.f, rintf(v[i].y / s))); ssum += q; o[i*4+1] = (char)(int)q;
    q = fminf(127.f, fmaxf(-127.f, rintf(v[i].z / s))); ssum += q; o[i*4+2] = (char)(int)q;
    q = fminf(127.f, fmaxf(-127.f, rintf(v[i].w / s))); ssum += q; o[i*4+3] = (char)(int)q;
  }
  *(c16*)(q2 + (size_t)t * HID + tid * 16) = o;
  red[tid] = ssum; __syncthreads();
  for (int off = 128; off > 0; off >>= 1) {
    if (tid < off) red[tid] += red[tid + off];
    __syncthreads();
  }
  if (tid == 0) { s2[t] = s; sum2[t] = red[0]; }
}

// ---------------- launch ----------------
extern "C" void kernel_launch(void* const* d_in, const int* in_sizes, int n_in,
                              void* d_out, int out_size, void* d_ws, size_t ws_size,
                              hipStream_t stream) {
  const int*   positions   = (const int*)d_in[0];
  const int*   q_act       = (const int*)d_in[1];
  const float* act_scale   = (const float*)d_in[2];
  const int*   w_qkv_q     = (const int*)d_in[3];
  const float* w_qkv_scale = (const float*)d_in[4];
  const float* w_qkv_zero  = (const float*)d_in[5];
  const int*   w_o_q       = (const int*)d_in[6];
  const float* w_o_scale   = (const float*)d_in[7];
  const float* w_o_zero    = (const float*)d_in[8];
  float* out = (float*)d_out;

  size_t off = 0;
  auto alloc = [&](size_t bytes) -> void* {
    void* p = (char*)d_ws + off;
    off += (bytes + 255) & ~(size_t)255;
    return p;
  };
  // mandatory (~118.6 MB)
  float* qkv   = (float*)alloc((size_t)T * QKV_OUT * 4);
  char*  a_i8  = (char*)alloc((size_t)T * HID);
  char*  q2    = (char*)alloc((size_t)T * HID);
  short* Kh    = (short*)alloc((size_t)NKV * T * HD * 2);
  short* Kl    = (short*)alloc((size_t)NKV * T * HD * 2);
  short* Vth   = (short*)alloc((size_t)NKV * T * HD * 2);
  short* Vtl   = (short*)alloc((size_t)NKV * T * HD * 2);
  short* op    = (short*)alloc((size_t)1024 * 4 * 32 * 128 * 2);
  float* ml    = (float*)alloc((size_t)1024 * 4 * 32 * 2 * 4);
  float* a_sum = (float*)alloc(T * 4);
  float* s2    = (float*)alloc(T * 4);
  float* sum2  = (float*)alloc(T * 4);
  // optional weight pre-pack
  char* wqkv_i8 = (char*)alloc((size_t)QKV_OUT * HID);
  char* wo_i8   = (char*)alloc((size_t)HID * HID);
  const bool wconv = (ws_size >= off);   // constant across calls

  asum_kernel<<<T, 256, 0, stream>>>(q_act, a_sum);
  conv_i2c<<<(T * HID / 16 + 255) / 256, 256, 0, stream>>>(q_act, a_i8, T * HID / 16);
  if (wconv) {
    conv_i2c<<<(QKV_OUT * HID / 16 + 255) / 256, 256, 0, stream>>>(w_qkv_q, wqkv_i8, QKV_OUT * HID / 16);
    conv_i2c<<<(HID * HID / 16 + 255) / 256, 256, 0, stream>>>(w_o_q, wo_i8, HID * HID / 16);
    gemm_i8<true><<<dim3(QKV_OUT / 128, T / 128), 256, 0, stream>>>(
        a_i8, wqkv_i8, act_scale, a_sum, w_qkv_scale, w_qkv_zero, qkv, T, QKV_OUT, HID);
  } else {
    gemm_i8<false><<<dim3(QKV_OUT / 128, T / 128), 256, 0, stream>>>(
        a_i8, w_qkv_q, act_scale, a_sum, w_qkv_scale, w_qkv_zero, qkv, T, QKV_OUT, HID);
  }
  rope_kernel<<<T * (NH + NKV), 64, 0, stream>>>(qkv, positions);
  split_kv<<<dim3(T / 64, NKV), 256, 0, stream>>>(qkv, Kh, Kl, Vth, Vtl);
  attn_kernel<<<dim3(T / 32 * 2, NKV), 256, 0, stream>>>(qkv, Kh, Kl, Vth, Vtl, op, ml);
  combine_kernel<<<T * NH * 32 / 256, 256, 0, stream>>>(op, ml, out);
  quant_kernel<<<T, 256, 0, stream>>>(out, q2, s2, sum2);
  if (wconv) {
    gemm_i8<true><<<dim3(HID / 128, T / 128), 256, 0, stream>>>(
        q2, wo_i8, s2, sum2, w_o_scale, w_o_zero, out, T, HID, HID);
  } else {
    gemm_i8<false><<<dim3(HID / 128, T / 128), 256, 0, stream>>>(
        q2, w_o_q, s2, sum2, w_o_scale, w_o_zero, out, T, HID, HID);
  }
}